// Round 11
// baseline (347.717 us; speedup 1.0000x reference)
//
#include <hip/hip_runtime.h>
#include <math.h>

#define B_ 4
#define N_ 256
#define D_ 128
#define H_ 256
#define K_ 8
#define KK 256    // GEMM K = [p (128) | sj (128)]
#define NJP 128   // j per phase (2 phases)

typedef short v8s __attribute__((ext_vector_type(8)));    // 8 bf16 = 4 VGPRs
typedef float v16f __attribute__((ext_vector_type(16)));  // 32x32 MFMA acc

// hi = top-16-bit truncation (x - hi is EXACT); lo = RNE bf16 of remainder.
__device__ inline void split_bf16(float x, unsigned short& hi, unsigned short& lo) {
  unsigned u = __float_as_uint(x);
  unsigned uh = u & 0xFFFF0000u;
  hi = (unsigned short)(uh >> 16);
  float r = x - __uint_as_float(uh);
  unsigned ur = __float_as_uint(r);
  ur += 0x7FFFu + ((ur >> 16) & 1u);
  lo = (unsigned short)(ur >> 16);
}

__global__ __launch_bounds__(256) void prep_an(
    const float* __restrict__ s,
    const float* __restrict__ Wg1, const float* __restrict__ bg1,
    const float* __restrict__ Wa1, const float* __restrict__ ba1,
    float* __restrict__ Ag, float* __restrict__ Aa,
    unsigned short* __restrict__ Shi, unsigned short* __restrict__ Slo) {
  const int b = blockIdx.x >> 8;
  const int n = blockIdx.x & 255;
  const int h = threadIdx.x;
  __shared__ float sh[D_];
  if (h < D_) sh[h] = s[(b * N_ + n) * D_ + h];
  __syncthreads();
  float ag = bg1[h], aa = ba1[h];
#pragma unroll 8
  for (int d = 0; d < D_; d++) {
    ag = fmaf(sh[d], Wg1[d * H_ + h], ag);
    aa = fmaf(sh[d], Wa1[d * H_ + h], aa);
  }
  Ag[(b * N_ + n) * H_ + h] = ag;
  Aa[(b * N_ + n) * H_ + h] = aa;
  if (h < D_) {
    unsigned short x, y;
    split_bf16(sh[h], x, y);
    Shi[(b * N_ + n) * D_ + h] = x;
    Slo[(b * N_ + n) * D_ + h] = y;
  }
}

// ---------------------------------------------------------------------------
// prep_sw: W in MFMA-B fragment order: [ks(16)][tile(8 of 32h)][lane(64)][8].
// In-loop B loads become base + lane*16 (fully coalesced).
// ---------------------------------------------------------------------------
__global__ __launch_bounds__(64) void prep_sw(
    const float* __restrict__ Wg1, const float* __restrict__ Wa1,
    unsigned short* __restrict__ Wghi, unsigned short* __restrict__ Wglo,
    unsigned short* __restrict__ Wahi) {
  const int ks = blockIdx.x >> 3;
  const int tile = blockIdx.x & 7;
  const int lane = threadIdx.x;
  const int h = tile * 32 + (lane & 31);
  const int kbase = ks * 16 + (lane >> 5) * 8;
  const int idx0 = (blockIdx.x * 64 + lane) * 8;
#pragma unroll
  for (int e = 0; e < 8; e++) {
    const int k = kbase + e;
    const int f = (k < D_) ? (2 * D_ + k) : k;
    unsigned short x, y;
    split_bf16(Wg1[f * H_ + h], x, y);
    Wghi[idx0 + e] = x;
    Wglo[idx0 + e] = y;
    unsigned short xa, ya;
    split_bf16(Wa1[f * H_ + h], xa, ya);
    Wahi[idx0 + e] = xa;
  }
}

__device__ inline void arg_better(float v2, int i2, float& v, int& idx) {
  if (v2 > v || (v2 == v && i2 < idx)) { v = v2; idx = i2; }
}

// LDS A-tile fragment-order index (hi half): jl (0..127), k (0..255)
//  [jt(4)][ks(16)][half(2)][m32(32)][e(8)] ; lo at +32768 shorts.
__device__ inline int a_idx(int jl, int k) {
  return (((jl >> 5) * 16 + (k >> 4)) * 64 + ((k >> 3) & 1) * 32 + (jl & 31)) * 8
         + (k & 7);
}
#define ALO 32768   // shorts offset of lo half

// ---------------------------------------------------------------------------
// score_kernel v11: 512 threads (8 waves), NJP=128, 2 phases.
// Wave wv owns gate h-tile wv and att h-tile wv (16 MFMA/ks, balanced) and
// 4 j-tiles (acc 64 AGPR per pass, passes share acc). Per-phase overheads
// (staging, barrier drains, B L2 traffic) halve vs v10; occupancy unchanged
// (8 waves/CU). B: v8-style 1-deep ping-pong with rolling pointers. A: LDS
// reads via rolling base + imm offsets (hi direct, lo via 2nd base).
// ---------------------------------------------------------------------------
__global__ __launch_bounds__(512, 2) void score_kernel(
    const float* __restrict__ s,
    const float* __restrict__ Ag, const float* __restrict__ Aa,
    const unsigned short* __restrict__ Shi, const unsigned short* __restrict__ Slo,
    const unsigned short* __restrict__ Wghi, const unsigned short* __restrict__ Wglo,
    const unsigned short* __restrict__ Wahi,
    const float* __restrict__ Wg2, const float* __restrict__ bg2p,
    const float* __restrict__ Wa2, const float* __restrict__ ba2p,
    float* __restrict__ out) {
  const int b = blockIdx.x >> 8;
  const int i = blockIdx.x & 255;
  const int t = threadIdx.x;
  const int wv = t >> 6, lane = t & 63;
  const int m32 = lane & 31, half32 = lane >> 5;

  __shared__ __align__(16) unsigned short a_all[2 * 32768 + 64]; // hi|lo 128KB
  __shared__ float si_sh[D_];
  __shared__ float agaa_sh[2 * H_];
  __shared__ float w2_sh[2 * H_];
  __shared__ float sc_part_g[8 * NJP];   // per-wave gate partials
  __shared__ float sc_part_a[8 * NJP];   // per-wave att partials
  __shared__ float scg_sh[N_];
  __shared__ float attl_sh[N_];
  __shared__ float red_v[8];
  __shared__ int red_i[8];
  __shared__ int sel_list[K_];

  if (t < D_) si_sh[t] = s[(b * N_ + i) * D_ + t];
  if (t < H_) {
    agaa_sh[t] = Ag[(b * N_ + i) * H_ + t];
    w2_sh[t] = Wg2[t];
  } else {
    agaa_sh[t] = Aa[(b * N_ + i) * H_ + (t - H_)];
    w2_sh[t] = Wa2[t - H_];
  }

  const int boff = (wv * 64 + lane) * 8;   // this wave's tile in W frag arrays

#pragma unroll 1
  for (int ph = 0; ph < 2; ph++) {
    __syncthreads();
    // ---- stage A tile (frag order): P hi/lo (k<128) + sj hi/lo (k>=128) ----
    {
      const int jl = t >> 2, kq = t & 3;    // 512 threads -> jl 0..127
      const int jg = b * N_ + ph * NJP + jl;
      const float* srow = s + jg * D_ + kq * 32;
      const float* sic = si_sh + kq * 32;
#pragma unroll
      for (int u = 0; u < 8; u++) {
        const float4 sv = *(const float4*)(srow + u * 4);
        unsigned short h0, h1, h2, h3, l0, l1, l2, l3;
        split_bf16(sic[u * 4 + 0] * sv.x, h0, l0);
        split_bf16(sic[u * 4 + 1] * sv.y, h1, l1);
        split_bf16(sic[u * 4 + 2] * sv.z, h2, l2);
        split_bf16(sic[u * 4 + 3] * sv.w, h3, l3);
        const int idx = a_idx(jl, kq * 32 + u * 4);
        *(unsigned*)(a_all + idx)           = (unsigned)h0 | ((unsigned)h1 << 16);
        *(unsigned*)(a_all + idx + 2)       = (unsigned)h2 | ((unsigned)h3 << 16);
        *(unsigned*)(a_all + ALO + idx)     = (unsigned)l0 | ((unsigned)l1 << 16);
        *(unsigned*)(a_all + ALO + idx + 2) = (unsigned)l2 | ((unsigned)l3 << 16);
      }
      const unsigned short* shr = Shi + jg * D_ + kq * 32;
      const unsigned short* slr = Slo + jg * D_ + kq * 32;
#pragma unroll
      for (int u = 0; u < 4; u++) {
        const int idx = a_idx(jl, 128 + kq * 32 + u * 8);
        *(v8s*)(a_all + idx)       = *(const v8s*)(shr + u * 8);
        *(v8s*)(a_all + ALO + idx) = *(const v8s*)(slr + u * 8);
      }
    }
    __syncthreads();

    // ================= pass G: gate (split-3), acc 64 regs =================
    {
      v16f acc[4];
#pragma unroll
      for (int jt = 0; jt < 4; jt++) acc[jt] = (v16f)(0.f);

      const unsigned short* pgh = Wghi + boff;
      const unsigned short* pgl = Wglo + boff;
      const unsigned short* ahi = a_all + lane * 8;          // rolling, +512/ks
      const unsigned short* alo = a_all + ALO + lane * 8;    // rolling
      v8s bh[2], bl[2];
      bh[0] = *(const v8s*)pgh;  pgh += 4096;
      bl[0] = *(const v8s*)pgl;  pgl += 4096;

#pragma unroll 2
      for (int ks = 0; ks < 16; ks++) {
        const int cur = ks & 1, nxt = cur ^ 1;
        bh[nxt] = *(const v8s*)pgh;  pgh += 4096;   // last reads pad (ws)
        bl[nxt] = *(const v8s*)pgl;  pgl += 4096;
        v8s ah0 = *(const v8s*)(ahi);
        v8s ah1 = *(const v8s*)(ahi + 8192);
        v8s ah2 = *(const v8s*)(ahi + 16384);
        v8s ah3 = *(const v8s*)(ahi + 24576);
        v8s al0 = *(const v8s*)(alo);
        v8s al1 = *(const v8s*)(alo + 8192);
        v8s al2 = *(const v8s*)(alo + 16384);
        v8s al3 = *(const v8s*)(alo + 24576);
        ahi += 512;  alo += 512;
        acc[0] = __builtin_amdgcn_mfma_f32_32x32x16_bf16(ah0, bh[cur], acc[0], 0, 0, 0);
        acc[1] = __builtin_amdgcn_mfma_f32_32x32x16_bf16(ah1, bh[cur], acc[1], 0, 0, 0);
        acc[2] = __builtin_amdgcn_mfma_f32_32x32x16_bf16(ah2, bh[cur], acc[2], 0, 0, 0);
        acc[3] = __builtin_amdgcn_mfma_f32_32x32x16_bf16(ah3, bh[cur], acc[3], 0, 0, 0);
        acc[0] = __builtin_amdgcn_mfma_f32_32x32x16_bf16(ah0, bl[cur], acc[0], 0, 0, 0);
        acc[1] = __builtin_amdgcn_mfma_f32_32x32x16_bf16(ah1, bl[cur], acc[1], 0, 0, 0);
        acc[2] = __builtin_amdgcn_mfma_f32_32x32x16_bf16(ah2, bl[cur], acc[2], 0, 0, 0);
        acc[3] = __builtin_amdgcn_mfma_f32_32x32x16_bf16(ah3, bl[cur], acc[3], 0, 0, 0);
        acc[0] = __builtin_amdgcn_mfma_f32_32x32x16_bf16(al0, bh[cur], acc[0], 0, 0, 0);
        acc[1] = __builtin_amdgcn_mfma_f32_32x32x16_bf16(al1, bh[cur], acc[1], 0, 0, 0);
        acc[2] = __builtin_amdgcn_mfma_f32_32x32x16_bf16(al2, bh[cur], acc[2], 0, 0, 0);
        acc[3] = __builtin_amdgcn_mfma_f32_32x32x16_bf16(al3, bh[cur], acc[3], 0, 0, 0);
      }
      // epilogue G: relu + W2 dot; butterfly over the 32 h-lanes
      const int hg = wv * 32 + m32;
      const float agv = agaa_sh[hg], w2g = w2_sh[hg];
      float sg[64];
#pragma unroll
      for (int jt = 0; jt < 4; jt++)
#pragma unroll
        for (int r = 0; r < 16; r++) {
          const float z = acc[jt][r] + agv;
          float v = fmaxf(z, 0.f) * w2g;
#pragma unroll
          for (int off = 1; off <= 16; off <<= 1) v += __shfl_xor(v, off, 64);
          sg[jt * 16 + r] = v;
        }
      if (m32 == 0) {
#pragma unroll
        for (int jt = 0; jt < 4; jt++)
#pragma unroll
          for (int r = 0; r < 16; r++) {
            const int jl = jt * 32 + (r & 3) + 8 * (r >> 2) + 4 * half32;
            sc_part_g[wv * NJP + jl] = sg[jt * 16 + r];
          }
      }
    }

    // ================= pass A: att (hi-only), acc 64 regs =================
    {
      v16f acc[4];
#pragma unroll
      for (int jt = 0; jt < 4; jt++) acc[jt] = (v16f)(0.f);

      const unsigned short* pah = Wahi + boff;
      const unsigned short* ahi = a_all + lane * 8;
      v8s bh[2];
      bh[0] = *(const v8s*)pah;  pah += 4096;

#pragma unroll 2
      for (int ks = 0; ks < 16; ks++) {
        const int cur = ks & 1, nxt = cur ^ 1;
        bh[nxt] = *(const v8s*)pah;  pah += 4096;
        v8s ah0 = *(const v8s*)(ahi);
        v8s ah1 = *(const v8s*)(ahi + 8192);
        v8s ah2 = *(const v8s*)(ahi + 16384);
        v8s ah3 = *(const v8s*)(ahi + 24576);
        ahi += 512;
        acc[0] = __builtin_amdgcn_mfma_f32_32x32x16_bf16(ah0, bh[cur], acc[0], 0, 0, 0);
        acc[1] = __builtin_amdgcn_mfma_f32_32x32x16_bf16(ah1, bh[cur], acc[1], 0, 0, 0);
        acc[2] = __builtin_amdgcn_mfma_f32_32x32x16_bf16(ah2, bh[cur], acc[2], 0, 0, 0);
        acc[3] = __builtin_amdgcn_mfma_f32_32x32x16_bf16(ah3, bh[cur], acc[3], 0, 0, 0);
      }
      // epilogue A
      const int ha = H_ + wv * 32 + m32;
      const float aav = agaa_sh[ha], w2a = w2_sh[ha];
      float sa[64];
#pragma unroll
      for (int jt = 0; jt < 4; jt++)
#pragma unroll
        for (int r = 0; r < 16; r++) {
          const float z = acc[jt][r] + aav;
          float v = fmaxf(z, 0.f) * w2a;
#pragma unroll
          for (int off = 1; off <= 16; off <<= 1) v += __shfl_xor(v, off, 64);
          sa[jt * 16 + r] = v;
        }
      if (m32 == 0) {
#pragma unroll
        for (int jt = 0; jt < 4; jt++)
#pragma unroll
          for (int r = 0; r < 16; r++) {
            const int jl = jt * 32 + (r & 3) + 8 * (r >> 2) + 4 * half32;
            sc_part_a[wv * NJP + jl] = sa[jt * 16 + r];
          }
      }
    }
    __syncthreads();
    if (t < NJP) {
      float g = bg2p[0], a = ba2p[0];
#pragma unroll
      for (int w = 0; w < 8; w++) {
        g += sc_part_g[w * NJP + t];
        a += sc_part_a[w * NJP + t];
      }
      scg_sh[ph * NJP + t] = g;
      attl_sh[ph * NJP + t] = a;
    }
  }
  __syncthreads();

  // ---- top-8 over j: value desc, index asc ----
  for (int k = 0; k < K_; k++) {
    float v = (t < N_) ? scg_sh[t] : -INFINITY;
    int idx = t;
#pragma unroll
    for (int off = 32; off > 0; off >>= 1) {
      const float vo = __shfl_down(v, off, 64);
      const int io = __shfl_down(idx, off, 64);
      arg_better(vo, io, v, idx);
    }
    if (lane == 0) { red_v[wv] = v; red_i[wv] = idx; }
    __syncthreads();
    if (t == 0) {
      float bv = red_v[0];
      int bi = red_i[0];
      for (int w = 1; w < 8; w++) arg_better(red_v[w], red_i[w], bv, bi);
      sel_list[k] = bi;
      scg_sh[bi] = -INFINITY;
    }
    __syncthreads();
  }

  bool selj = false;
#pragma unroll
  for (int k = 0; k < K_; k++) selj = selj || (sel_list[k] == t);

  if (t == 0) {
    float m = -INFINITY;
    for (int k = 0; k < K_; k++) m = fmaxf(m, attl_sh[sel_list[k]]);
    float ssum = 0.f;
    for (int k = 0; k < K_; k++) ssum += expf(attl_sh[sel_list[k]] - m);
    red_v[0] = m;
    red_v[1] = ssum;
  }
  __syncthreads();

  float* __restrict__ ctx_out = out;
  float* __restrict__ gate_out = out + B_ * N_ * D_;
  float* __restrict__ att_out = out + B_ * N_ * D_ + B_ * N_ * N_;

  float att = 0.f;
  if (t < N_) {
    att = selj ? expf(attl_sh[t] - red_v[0]) / red_v[1] : 0.f;
    const int row = (b * N_ + i) * N_;
    gate_out[row + t] = selj ? 1.f : 0.f;
    att_out[row + t] = att;
  }
  __syncthreads();
  if (t < N_) attl_sh[t] = att;
  __syncthreads();

  if (t < D_) {
    float acc2 = 0.f;
#pragma unroll
    for (int k = 0; k < K_; k++) {
      const int jj = sel_list[k];
      acc2 = fmaf(attl_sh[jj], s[(b * N_ + jj) * D_ + t], acc2);
    }
    ctx_out[(b * N_ + i) * D_ + t] = acc2;
  }
}

extern "C" void kernel_launch(void* const* d_in, const int* in_sizes, int n_in,
                              void* d_out, int out_size, void* d_ws, size_t ws_size,
                              hipStream_t stream) {
  const float* s   = (const float*)d_in[0];
  const float* Wg1 = (const float*)d_in[1];
  const float* bg1 = (const float*)d_in[2];
  const float* Wg2 = (const float*)d_in[3];
  const float* bg2 = (const float*)d_in[4];
  const float* Wa1 = (const float*)d_in[5];
  const float* ba1 = (const float*)d_in[6];
  const float* Wa2 = (const float*)d_in[7];
  const float* ba2 = (const float*)d_in[8];
  float* out = (float*)d_out;

  float* ws = (float*)d_ws;
  float* Ag = ws;                                        // B*N*H floats
  float* Aa = Ag + B_ * N_ * H_;                         // B*N*H floats
  unsigned short* Shi  = (unsigned short*)(Aa + B_ * N_ * H_);  // B*N*D
  unsigned short* Slo  = Shi + B_ * N_ * D_;
  // W arrays padded by 4096 shorts: 1-deep ks-prefetch reads past the end.
  unsigned short* Wghi = Slo + B_ * N_ * D_;             // 65536 + 4096 pad
  unsigned short* Wglo = Wghi + 65536 + 4096;
  unsigned short* Wahi = Wglo + 65536 + 4096;

  prep_an<<<dim3(B_ * N_), dim3(256), 0, stream>>>(
      s, Wg1, bg1, Wa1, ba1, Ag, Aa, Shi, Slo);
  prep_sw<<<dim3(128), dim3(64), 0, stream>>>(Wg1, Wa1, Wghi, Wglo, Wahi);
  score_kernel<<<dim3(B_ * N_), dim3(512), 0, stream>>>(
      s, Ag, Aa, Shi, Slo, Wghi, Wglo, Wahi, Wg2, bg2, Wa2, ba2, out);
}

// Round 12
// 264.500 us; speedup vs baseline: 1.3146x; 1.3146x over previous
//
#include <hip/hip_runtime.h>
#include <math.h>

#define B_ 4
#define N_ 256
#define D_ 128
#define H_ 256
#define K_ 8
#define KK 256    // GEMM K = [p (128) | sj (128)]
#define NJP 64    // j per phase (4 phases)

typedef short v8s __attribute__((ext_vector_type(8)));    // 8 bf16 = 4 VGPRs
typedef float v16f __attribute__((ext_vector_type(16)));  // 32x32 MFMA acc

// hi = top-16-bit truncation (x - hi is EXACT); lo = RNE bf16 of remainder.
__device__ inline void split_bf16(float x, unsigned short& hi, unsigned short& lo) {
  unsigned u = __float_as_uint(x);
  unsigned uh = u & 0xFFFF0000u;
  hi = (unsigned short)(uh >> 16);
  float r = x - __uint_as_float(uh);
  unsigned ur = __float_as_uint(r);
  ur += 0x7FFFu + ((ur >> 16) & 1u);
  lo = (unsigned short)(ur >> 16);
}

__global__ __launch_bounds__(256) void prep_an(
    const float* __restrict__ s,
    const float* __restrict__ Wg1, const float* __restrict__ bg1,
    const float* __restrict__ Wa1, const float* __restrict__ ba1,
    float* __restrict__ Ag, float* __restrict__ Aa,
    unsigned short* __restrict__ Shi, unsigned short* __restrict__ Slo) {
  const int b = blockIdx.x >> 8;
  const int n = blockIdx.x & 255;
  const int h = threadIdx.x;
  __shared__ float sh[D_];
  if (h < D_) sh[h] = s[(b * N_ + n) * D_ + h];
  __syncthreads();
  float ag = bg1[h], aa = ba1[h];
#pragma unroll 8
  for (int d = 0; d < D_; d++) {
    ag = fmaf(sh[d], Wg1[d * H_ + h], ag);
    aa = fmaf(sh[d], Wa1[d * H_ + h], aa);
  }
  Ag[(b * N_ + n) * H_ + h] = ag;
  Aa[(b * N_ + n) * H_ + h] = aa;
  if (h < D_) {
    unsigned short x, y;
    split_bf16(sh[h], x, y);
    Shi[(b * N_ + n) * D_ + h] = x;
    Slo[(b * N_ + n) * D_ + h] = y;
  }
}

// ---------------------------------------------------------------------------
// prep_sw: W in MFMA-B fragment order: [ks(16)][tile(8 of 32h)][lane(64)][8].
// ---------------------------------------------------------------------------
__global__ __launch_bounds__(64) void prep_sw(
    const float* __restrict__ Wg1, const float* __restrict__ Wa1,
    unsigned short* __restrict__ Wghi, unsigned short* __restrict__ Wglo,
    unsigned short* __restrict__ Wahi) {
  const int ks = blockIdx.x >> 3;
  const int tile = blockIdx.x & 7;
  const int lane = threadIdx.x;
  const int h = tile * 32 + (lane & 31);
  const int kbase = ks * 16 + (lane >> 5) * 8;
  const int idx0 = (blockIdx.x * 64 + lane) * 8;
#pragma unroll
  for (int e = 0; e < 8; e++) {
    const int k = kbase + e;
    const int f = (k < D_) ? (2 * D_ + k) : k;
    unsigned short x, y;
    split_bf16(Wg1[f * H_ + h], x, y);
    Wghi[idx0 + e] = x;
    Wglo[idx0 + e] = y;
    unsigned short xa, ya;
    split_bf16(Wa1[f * H_ + h], xa, ya);
    Wahi[idx0 + e] = xa;
  }
}

// ---------------------------------------------------------------------------
// prep_sf: sj half of the A operand (k>=128) is i-INDEPENDENT -> pre-swizzle
// into global MFMA-A fragment order [b][jt(8 of 32j)][ksl(8)][lane(64)][8]
// so score_kernel reads it as coalesced rolling streams (no LDS needed).
// Fragment content: j = jt*32+(lane&31), d = ksl*16+(lane>>5)*8+e.
// ---------------------------------------------------------------------------
__global__ __launch_bounds__(256) void prep_sf(
    const unsigned short* __restrict__ Shi, const unsigned short* __restrict__ Slo,
    unsigned short* __restrict__ Sfh, unsigned short* __restrict__ Sfl) {
  const int b = blockIdx.x >> 3, jt = blockIdx.x & 7;
  const int lane = threadIdx.x & 63;
  const int k0 = threadIdx.x >> 6;   // 0..3
  const int j = jt * 32 + (lane & 31);
#pragma unroll
  for (int ksl = k0; ksl < 8; ksl += 4) {
    const int d = ksl * 16 + (lane >> 5) * 8;
    const int src = (b * N_ + j) * D_ + d;
    const int dst = (((b * 8 + jt) * 8 + ksl) * 64 + lane) * 8;
    *(v8s*)(Sfh + dst) = *(const v8s*)(Shi + src);
    *(v8s*)(Sfl + dst) = *(const v8s*)(Slo + src);
  }
}

__device__ inline void arg_better(float v2, int i2, float& v, int& idx) {
  if (v2 > v || (v2 == v && i2 < idx)) { v = v2; idx = i2; }
}

// LDS A-tile (P part only, k<128) fragment-order index: jl (0..63), k (0..127)
//  [jt(2)][ks(8)][half(2)][m32(32)][e(8)] ; lo at +8192 shorts.
__device__ inline int a_idx(int jl, int k) {
  return (((jl >> 5) * 8 + (k >> 4)) * 64 + ((k >> 3) & 1) * 32 + (jl & 31)) * 8
         + (k & 7);
}
#define ALO 8192   // shorts offset of lo half

// ---------------------------------------------------------------------------
// score_kernel v12: v10 structure, occupancy-focused:
//  - LDS A-tile holds only the P part (32 KB); sj part streams from global
//    pre-swizzled frag arrays (loop2). agaa/w2 epilogue tables preloaded
//    into VGPRs (h index is phase-independent). LDS ~37 KB -> 3+ blocks/CU.
//  - B tiles: one rolling pointer per array, tile1 at +1024 B imm.
// ---------------------------------------------------------------------------
__global__ __launch_bounds__(256, 2) void score_kernel(
    const float* __restrict__ s,
    const float* __restrict__ Ag, const float* __restrict__ Aa,
    const unsigned short* __restrict__ Shi, const unsigned short* __restrict__ Slo,
    const unsigned short* __restrict__ Sfh, const unsigned short* __restrict__ Sfl,
    const unsigned short* __restrict__ Wghi, const unsigned short* __restrict__ Wglo,
    const unsigned short* __restrict__ Wahi,
    const float* __restrict__ Wg2, const float* __restrict__ bg2p,
    const float* __restrict__ Wa2, const float* __restrict__ ba2p,
    float* __restrict__ out) {
  const int b = blockIdx.x >> 8;
  const int i = blockIdx.x & 255;
  const int t = threadIdx.x;
  const int wv = t >> 6, lane = t & 63;
  const int m32 = lane & 31, half32 = lane >> 5;

  __shared__ __align__(16) unsigned short a_all[2 * 8192 + 64]; // P hi|lo 32KB
  __shared__ float si_sh[D_];
  __shared__ float sc_part[8 * NJP];   // [0..3]=gate per wave, [4..7]=att
  __shared__ float scg_sh[N_];
  __shared__ float attl_sh[N_];
  __shared__ float red_v[4];
  __shared__ int red_i[4];
  __shared__ int sel_list[K_];

  if (t < D_) si_sh[t] = s[(b * N_ + i) * D_ + t];

  // epilogue tables in VGPRs (phase-independent h index)
  float agv[2], w2g[2], aav[2], w2a[2];
#pragma unroll
  for (int ht = 0; ht < 2; ht++) {
    const int hg = wv * 64 + ht * 32 + m32;
    agv[ht] = Ag[(b * N_ + i) * H_ + hg];
    w2g[ht] = Wg2[hg];
    aav[ht] = Aa[(b * N_ + i) * H_ + hg];
    w2a[ht] = Wa2[hg];
  }

  const int boff = ((2 * wv) * 64 + lane) * 8;   // tile pair base; +512 = tile1

#pragma unroll 1
  for (int ph = 0; ph < 4; ph++) {
    __syncthreads();
    // ---- stage P tile (frag order, k<128 only), 16-B LDS writes ----
    {
      const int jl = t >> 2, kq = t & 3;
      const int jg = b * N_ + ph * NJP + jl;
      const float* srow = s + jg * D_ + kq * 32;
      const float* sic = si_sh + kq * 32;
#pragma unroll
      for (int u = 0; u < 4; u++) {   // 8 k per u
        const float4 sv0 = *(const float4*)(srow + u * 8);
        const float4 sv1 = *(const float4*)(srow + u * 8 + 4);
        unsigned short hh[8], ll[8];
        split_bf16(sic[u * 8 + 0] * sv0.x, hh[0], ll[0]);
        split_bf16(sic[u * 8 + 1] * sv0.y, hh[1], ll[1]);
        split_bf16(sic[u * 8 + 2] * sv0.z, hh[2], ll[2]);
        split_bf16(sic[u * 8 + 3] * sv0.w, hh[3], ll[3]);
        split_bf16(sic[u * 8 + 4] * sv1.x, hh[4], ll[4]);
        split_bf16(sic[u * 8 + 5] * sv1.y, hh[5], ll[5]);
        split_bf16(sic[u * 8 + 6] * sv1.z, hh[6], ll[6]);
        split_bf16(sic[u * 8 + 7] * sv1.w, hh[7], ll[7]);
        v8s vh, vl;
#pragma unroll
        for (int e = 0; e < 8; e++) { vh[e] = (short)hh[e]; vl[e] = (short)ll[e]; }
        const int idx = a_idx(jl, kq * 32 + u * 8);
        *(v8s*)(a_all + idx) = vh;
        *(v8s*)(a_all + ALO + idx) = vl;
      }
    }
    __syncthreads();

    const unsigned short* sf_base_h = Sfh + ((b * 8 + ph * 2) * 8) * 512 + lane * 8;
    const unsigned short* sf_base_l = Sfl + ((b * 8 + ph * 2) * 8) * 512 + lane * 8;

    // ================= pass G: gate (split-3), acc 64 regs =================
    {
      v16f acc[2][2];
#pragma unroll
      for (int jt = 0; jt < 2; jt++)
#pragma unroll
        for (int ht = 0; ht < 2; ht++) acc[jt][ht] = (v16f)(0.f);

      const unsigned short* pgh = Wghi + boff;
      const unsigned short* pgl = Wglo + boff;
      v8s bh[2][2], bl[2][2];
      bh[0][0] = *(const v8s*)pgh;  bh[0][1] = *(const v8s*)(pgh + 512);
      bl[0][0] = *(const v8s*)pgl;  bl[0][1] = *(const v8s*)(pgl + 512);
      pgh += 4096;  pgl += 4096;

      const unsigned short* ahp = a_all + lane * 8;   // LDS rolling base
      // ---- loop1: ks 0..7, A from LDS (P part) ----
#pragma unroll 2
      for (int ks = 0; ks < 8; ks++) {
        const int cur = ks & 1, nxt = cur ^ 1;
        bh[nxt][0] = *(const v8s*)pgh;  bh[nxt][1] = *(const v8s*)(pgh + 512);
        bl[nxt][0] = *(const v8s*)pgl;  bl[nxt][1] = *(const v8s*)(pgl + 512);
        pgh += 4096;  pgl += 4096;
        v8s ah0 = *(const v8s*)(ahp);
        v8s ah1 = *(const v8s*)(ahp + 4096);
        v8s al0 = *(const v8s*)(ahp + ALO);
        v8s al1 = *(const v8s*)(ahp + ALO + 4096);
        ahp += 512;
        acc[0][0] = __builtin_amdgcn_mfma_f32_32x32x16_bf16(ah0, bh[cur][0], acc[0][0], 0, 0, 0);
        acc[0][1] = __builtin_amdgcn_mfma_f32_32x32x16_bf16(ah0, bh[cur][1], acc[0][1], 0, 0, 0);
        acc[0][0] = __builtin_amdgcn_mfma_f32_32x32x16_bf16(ah0, bl[cur][0], acc[0][0], 0, 0, 0);
        acc[0][1] = __builtin_amdgcn_mfma_f32_32x32x16_bf16(ah0, bl[cur][1], acc[0][1], 0, 0, 0);
        acc[0][0] = __builtin_amdgcn_mfma_f32_32x32x16_bf16(al0, bh[cur][0], acc[0][0], 0, 0, 0);
        acc[0][1] = __builtin_amdgcn_mfma_f32_32x32x16_bf16(al0, bh[cur][1], acc[0][1], 0, 0, 0);
        acc[1][0] = __builtin_amdgcn_mfma_f32_32x32x16_bf16(ah1, bh[cur][0], acc[1][0], 0, 0, 0);
        acc[1][1] = __builtin_amdgcn_mfma_f32_32x32x16_bf16(ah1, bh[cur][1], acc[1][1], 0, 0, 0);
        acc[1][0] = __builtin_amdgcn_mfma_f32_32x32x16_bf16(ah1, bl[cur][0], acc[1][0], 0, 0, 0);
        acc[1][1] = __builtin_amdgcn_mfma_f32_32x32x16_bf16(ah1, bl[cur][1], acc[1][1], 0, 0, 0);
        acc[1][0] = __builtin_amdgcn_mfma_f32_32x32x16_bf16(al1, bh[cur][0], acc[1][0], 0, 0, 0);
        acc[1][1] = __builtin_amdgcn_mfma_f32_32x32x16_bf16(al1, bh[cur][1], acc[1][1], 0, 0, 0);
      }
      // ---- loop2: ks 8..15, A from global sj frag streams ----
      const unsigned short* sfh = sf_base_h;
      const unsigned short* sfl = sf_base_l;
#pragma unroll 2
      for (int ks = 8; ks < 16; ks++) {
        const int cur = ks & 1, nxt = cur ^ 1;
        bh[nxt][0] = *(const v8s*)pgh;  bh[nxt][1] = *(const v8s*)(pgh + 512);
        bl[nxt][0] = *(const v8s*)pgl;  bl[nxt][1] = *(const v8s*)(pgl + 512);
        pgh += 4096;  pgl += 4096;   // last iter reads pad - harmless
        v8s ah0 = *(const v8s*)(sfh);
        v8s ah1 = *(const v8s*)(sfh + 4096);
        v8s al0 = *(const v8s*)(sfl);
        v8s al1 = *(const v8s*)(sfl + 4096);
        sfh += 512;  sfl += 512;
        acc[0][0] = __builtin_amdgcn_mfma_f32_32x32x16_bf16(ah0, bh[cur][0], acc[0][0], 0, 0, 0);
        acc[0][1] = __builtin_amdgcn_mfma_f32_32x32x16_bf16(ah0, bh[cur][1], acc[0][1], 0, 0, 0);
        acc[0][0] = __builtin_amdgcn_mfma_f32_32x32x16_bf16(ah0, bl[cur][0], acc[0][0], 0, 0, 0);
        acc[0][1] = __builtin_amdgcn_mfma_f32_32x32x16_bf16(ah0, bl[cur][1], acc[0][1], 0, 0, 0);
        acc[0][0] = __builtin_amdgcn_mfma_f32_32x32x16_bf16(al0, bh[cur][0], acc[0][0], 0, 0, 0);
        acc[0][1] = __builtin_amdgcn_mfma_f32_32x32x16_bf16(al0, bh[cur][1], acc[0][1], 0, 0, 0);
        acc[1][0] = __builtin_amdgcn_mfma_f32_32x32x16_bf16(ah1, bh[cur][0], acc[1][0], 0, 0, 0);
        acc[1][1] = __builtin_amdgcn_mfma_f32_32x32x16_bf16(ah1, bh[cur][1], acc[1][1], 0, 0, 0);
        acc[1][0] = __builtin_amdgcn_mfma_f32_32x32x16_bf16(ah1, bl[cur][0], acc[1][0], 0, 0, 0);
        acc[1][1] = __builtin_amdgcn_mfma_f32_32x32x16_bf16(ah1, bl[cur][1], acc[1][1], 0, 0, 0);
        acc[1][0] = __builtin_amdgcn_mfma_f32_32x32x16_bf16(al1, bh[cur][0], acc[1][0], 0, 0, 0);
        acc[1][1] = __builtin_amdgcn_mfma_f32_32x32x16_bf16(al1, bh[cur][1], acc[1][1], 0, 0, 0);
      }
      // epilogue G
      float sg[32];
#pragma unroll
      for (int m = 0; m < 32; m++) sg[m] = 0.f;
#pragma unroll
      for (int ht = 0; ht < 2; ht++)
#pragma unroll
        for (int jt = 0; jt < 2; jt++)
#pragma unroll
          for (int r = 0; r < 16; r++) {
            const float z = acc[jt][ht][r] + agv[ht];
            sg[jt * 16 + r] = fmaf(fmaxf(z, 0.f), w2g[ht], sg[jt * 16 + r]);
          }
#pragma unroll
      for (int m = 0; m < 32; m++) {
        float v = sg[m];
#pragma unroll
        for (int off = 1; off <= 16; off <<= 1) v += __shfl_xor(v, off, 64);
        sg[m] = v;
      }
      if (m32 == 0) {
#pragma unroll
        for (int jt = 0; jt < 2; jt++)
#pragma unroll
          for (int r = 0; r < 16; r++) {
            const int jl = jt * 32 + (r & 3) + 8 * (r >> 2) + 4 * half32;
            sc_part[wv * NJP + jl] = sg[jt * 16 + r];
          }
      }
    }

    // ================= pass A: att (hi-only), acc 64 regs =================
    {
      v16f acc[2][2];
#pragma unroll
      for (int jt = 0; jt < 2; jt++)
#pragma unroll
        for (int ht = 0; ht < 2; ht++) acc[jt][ht] = (v16f)(0.f);

      const unsigned short* pah = Wahi + boff;
      v8s bh[2][2];
      bh[0][0] = *(const v8s*)pah;  bh[0][1] = *(const v8s*)(pah + 512);
      pah += 4096;

      const unsigned short* ahp = a_all + lane * 8;
#pragma unroll 2
      for (int ks = 0; ks < 8; ks++) {
        const int cur = ks & 1, nxt = cur ^ 1;
        bh[nxt][0] = *(const v8s*)pah;  bh[nxt][1] = *(const v8s*)(pah + 512);
        pah += 4096;
        v8s ah0 = *(const v8s*)(ahp);
        v8s ah1 = *(const v8s*)(ahp + 4096);
        ahp += 512;
        acc[0][0] = __builtin_amdgcn_mfma_f32_32x32x16_bf16(ah0, bh[cur][0], acc[0][0], 0, 0, 0);
        acc[0][1] = __builtin_amdgcn_mfma_f32_32x32x16_bf16(ah0, bh[cur][1], acc[0][1], 0, 0, 0);
        acc[1][0] = __builtin_amdgcn_mfma_f32_32x32x16_bf16(ah1, bh[cur][0], acc[1][0], 0, 0, 0);
        acc[1][1] = __builtin_amdgcn_mfma_f32_32x32x16_bf16(ah1, bh[cur][1], acc[1][1], 0, 0, 0);
      }
      const unsigned short* sfh = sf_base_h;
#pragma unroll 2
      for (int ks = 8; ks < 16; ks++) {
        const int cur = ks & 1, nxt = cur ^ 1;
        bh[nxt][0] = *(const v8s*)pah;  bh[nxt][1] = *(const v8s*)(pah + 512);
        pah += 4096;   // last iter reads pad
        v8s ah0 = *(const v8s*)(sfh);
        v8s ah1 = *(const v8s*)(sfh + 4096);
        sfh += 512;
        acc[0][0] = __builtin_amdgcn_mfma_f32_32x32x16_bf16(ah0, bh[cur][0], acc[0][0], 0, 0, 0);
        acc[0][1] = __builtin_amdgcn_mfma_f32_32x32x16_bf16(ah0, bh[cur][1], acc[0][1], 0, 0, 0);
        acc[1][0] = __builtin_amdgcn_mfma_f32_32x32x16_bf16(ah1, bh[cur][0], acc[1][0], 0, 0, 0);
        acc[1][1] = __builtin_amdgcn_mfma_f32_32x32x16_bf16(ah1, bh[cur][1], acc[1][1], 0, 0, 0);
      }
      // epilogue A
      float sa[32];
#pragma unroll
      for (int m = 0; m < 32; m++) sa[m] = 0.f;
#pragma unroll
      for (int ht = 0; ht < 2; ht++)
#pragma unroll
        for (int jt = 0; jt < 2; jt++)
#pragma unroll
          for (int r = 0; r < 16; r++) {
            const float z = acc[jt][ht][r] + aav[ht];
            sa[jt * 16 + r] = fmaf(fmaxf(z, 0.f), w2a[ht], sa[jt * 16 + r]);
          }
#pragma unroll
      for (int m = 0; m < 32; m++) {
        float v = sa[m];
#pragma unroll
        for (int off = 1; off <= 16; off <<= 1) v += __shfl_xor(v, off, 64);
        sa[m] = v;
      }
      if (m32 == 0) {
#pragma unroll
        for (int jt = 0; jt < 2; jt++)
#pragma unroll
          for (int r = 0; r < 16; r++) {
            const int jl = jt * 32 + (r & 3) + 8 * (r >> 2) + 4 * half32;
            sc_part[4 * NJP + wv * NJP + jl] = sa[jt * 16 + r];
          }
      }
    }
    __syncthreads();
    if (t < NJP) {
      scg_sh[ph * NJP + t] = sc_part[t] + sc_part[NJP + t] + sc_part[2 * NJP + t]
                           + sc_part[3 * NJP + t] + bg2p[0];
      attl_sh[ph * NJP + t] = sc_part[4 * NJP + t] + sc_part[5 * NJP + t]
                            + sc_part[6 * NJP + t] + sc_part[7 * NJP + t] + ba2p[0];
    }
  }
  __syncthreads();

  // ---- top-8 over j: value desc, index asc ----
  for (int k = 0; k < K_; k++) {
    float v = scg_sh[t];
    int idx = t;
#pragma unroll
    for (int off = 32; off > 0; off >>= 1) {
      const float vo = __shfl_down(v, off, 64);
      const int io = __shfl_down(idx, off, 64);
      arg_better(vo, io, v, idx);
    }
    if ((t & 63) == 0) { red_v[t >> 6] = v; red_i[t >> 6] = idx; }
    __syncthreads();
    if (t == 0) {
      float bv = red_v[0];
      int bi = red_i[0];
      for (int w = 1; w < 4; w++) arg_better(red_v[w], red_i[w], bv, bi);
      sel_list[k] = bi;
      scg_sh[bi] = -INFINITY;
    }
    __syncthreads();
  }

  bool selj = false;
#pragma unroll
  for (int k = 0; k < K_; k++) selj = selj || (sel_list[k] == t);

  if (t == 0) {
    float m = -INFINITY;
    for (int k = 0; k < K_; k++) m = fmaxf(m, attl_sh[sel_list[k]]);
    float ssum = 0.f;
    for (int k = 0; k < K_; k++) ssum += expf(attl_sh[sel_list[k]] - m);
    red_v[0] = m;
    red_v[1] = ssum;
  }
  __syncthreads();
  const float att = selj ? expf(attl_sh[t] - red_v[0]) / red_v[1] : 0.f;

  float* __restrict__ ctx_out = out;
  float* __restrict__ gate_out = out + B_ * N_ * D_;
  float* __restrict__ att_out = out + B_ * N_ * D_ + B_ * N_ * N_;

  const int row = (b * N_ + i) * N_;
  gate_out[row + t] = selj ? 1.f : 0.f;
  att_out[row + t] = att;

  __syncthreads();
  attl_sh[t] = att;
  __syncthreads();

  if (t < D_) {
    float acc2 = 0.f;
#pragma unroll
    for (int k = 0; k < K_; k++) {
      const int jj = sel_list[k];
      acc2 = fmaf(attl_sh[jj], s[(b * N_ + jj) * D_ + t], acc2);
    }
    ctx_out[(b * N_ + i) * D_ + t] = acc2;
  }
}

extern "C" void kernel_launch(void* const* d_in, const int* in_sizes, int n_in,
                              void* d_out, int out_size, void* d_ws, size_t ws_size,
                              hipStream_t stream) {
  const float* s   = (const float*)d_in[0];
  const float* Wg1 = (const float*)d_in[1];
  const float* bg1 = (const float*)d_in[2];
  const float* Wg2 = (const float*)d_in[3];
  const float* bg2 = (const float*)d_in[4];
  const float* Wa1 = (const float*)d_in[5];
  const float* ba1 = (const float*)d_in[6];
  const float* Wa2 = (const float*)d_in[7];
  const float* ba2 = (const float*)d_in[8];
  float* out = (float*)d_out;

  float* ws = (float*)d_ws;
  float* Ag = ws;                                        // B*N*H floats
  float* Aa = Ag + B_ * N_ * H_;                         // B*N*H floats
  unsigned short* Shi  = (unsigned short*)(Aa + B_ * N_ * H_);  // B*N*D
  unsigned short* Slo  = Shi + B_ * N_ * D_;
  // W arrays padded by 4096 shorts: 1-deep ks-prefetch reads past the end.
  unsigned short* Wghi = Slo + B_ * N_ * D_;             // 65536 + 4096 pad
  unsigned short* Wglo = Wghi + 65536 + 4096;
  unsigned short* Wahi = Wglo + 65536 + 4096;
  unsigned short* Sfh  = Wahi + 65536 + 4096;            // B*8*8*64*8 = 131072
  unsigned short* Sfl  = Sfh + B_ * 32768;

  prep_an<<<dim3(B_ * N_), dim3(256), 0, stream>>>(
      s, Wg1, bg1, Wa1, ba1, Ag, Aa, Shi, Slo);
  prep_sw<<<dim3(128), dim3(64), 0, stream>>>(Wg1, Wa1, Wghi, Wglo, Wahi);
  prep_sf<<<dim3(B_ * 8), dim3(256), 0, stream>>>(Shi, Slo, Sfh, Sfl);
  score_kernel<<<dim3(B_ * N_), dim3(256), 0, stream>>>(
      s, Ag, Aa, Shi, Slo, Sfh, Sfl, Wghi, Wglo, Wahi, Wg2, bg2, Wa2, ba2, out);
}

// Round 13
// 248.378 us; speedup vs baseline: 1.4000x; 1.0649x over previous
//
#include <hip/hip_runtime.h>
#include <math.h>

#define B_ 4
#define N_ 256
#define D_ 128
#define H_ 256
#define K_ 8
#define NJP 64    // j per phase (4 phases)

typedef short v8s __attribute__((ext_vector_type(8)));    // 8 bf16 = 4 VGPRs
typedef float v16f __attribute__((ext_vector_type(16)));  // 32x32 MFMA acc

// hi = top-16-bit truncation (x - hi is EXACT); lo = RNE bf16 of remainder.
__device__ inline void split_bf16(float x, unsigned short& hi, unsigned short& lo) {
  unsigned u = __float_as_uint(x);
  unsigned uh = u & 0xFFFF0000u;
  hi = (unsigned short)(uh >> 16);
  float r = x - __uint_as_float(uh);
  unsigned ur = __float_as_uint(r);
  ur += 0x7FFFu + ((ur >> 16) & 1u);
  lo = (unsigned short)(ur >> 16);
}

// ---------------------------------------------------------------------------
// prep_all: ONE launch for all preprocessing (was 3 — ~58us of the 264 total
// was prep+launch overhead).
//  blocks 0..1023   : Ag/Aa (i-side first-layer terms, bias folded)
//  blocks 1024..1151: W -> MFMA-B fragment order [ks(16)][tile(8)][lane][8]
//  blocks 1152..1183: sj half of A (i-independent) -> MFMA-A fragment order
//                     [b][jt(8)][ksl(8)][lane][8], split from s directly.
// ---------------------------------------------------------------------------
__global__ __launch_bounds__(256) void prep_all(
    const float* __restrict__ s,
    const float* __restrict__ Wg1, const float* __restrict__ bg1,
    const float* __restrict__ Wa1, const float* __restrict__ ba1,
    float* __restrict__ Ag, float* __restrict__ Aa,
    unsigned short* __restrict__ Wghi, unsigned short* __restrict__ Wglo,
    unsigned short* __restrict__ Wahi,
    unsigned short* __restrict__ Sfh, unsigned short* __restrict__ Sfl) {
  __shared__ float sh[D_];
  const int blk = blockIdx.x;
  if (blk < 1024) {
    const int b = blk >> 8, n = blk & 255, h = threadIdx.x;
    if (h < D_) sh[h] = s[(b * N_ + n) * D_ + h];
    __syncthreads();
    float ag = bg1[h], aa = ba1[h];
#pragma unroll 8
    for (int d = 0; d < D_; d++) {
      ag = fmaf(sh[d], Wg1[d * H_ + h], ag);
      aa = fmaf(sh[d], Wa1[d * H_ + h], aa);
    }
    Ag[(b * N_ + n) * H_ + h] = ag;
    Aa[(b * N_ + n) * H_ + h] = aa;
  } else if (blk < 1152) {
    const int id = blk - 1024;          // 0..127
    if (threadIdx.x < 64) {
      const int ks = id >> 3, tile = id & 7, lane = threadIdx.x;
      const int h = tile * 32 + (lane & 31);
      const int kbase = ks * 16 + (lane >> 5) * 8;
      const int idx0 = (id * 64 + lane) * 8;
#pragma unroll
      for (int e = 0; e < 8; e++) {
        const int k = kbase + e;
        const int f = (k < D_) ? (2 * D_ + k) : k;
        unsigned short x, y;
        split_bf16(Wg1[f * H_ + h], x, y);
        Wghi[idx0 + e] = x;
        Wglo[idx0 + e] = y;
        unsigned short xa, ya;
        split_bf16(Wa1[f * H_ + h], xa, ya);
        Wahi[idx0 + e] = xa;
      }
    }
  } else {
    const int id = blk - 1152;          // 0..31
    const int b = id >> 3, jt = id & 7;
    const int lane = threadIdx.x & 63, k0 = threadIdx.x >> 6;
    const int j = jt * 32 + (lane & 31);
#pragma unroll
    for (int ksl = k0; ksl < 8; ksl += 4) {
      const int d = ksl * 16 + (lane >> 5) * 8;
      const float* sp = s + (b * N_ + j) * D_ + d;
      const float4 f0 = *(const float4*)(sp);
      const float4 f1 = *(const float4*)(sp + 4);
      v8s vh, vl;
      unsigned short x, y;
      split_bf16(f0.x, x, y); vh[0] = (short)x; vl[0] = (short)y;
      split_bf16(f0.y, x, y); vh[1] = (short)x; vl[1] = (short)y;
      split_bf16(f0.z, x, y); vh[2] = (short)x; vl[2] = (short)y;
      split_bf16(f0.w, x, y); vh[3] = (short)x; vl[3] = (short)y;
      split_bf16(f1.x, x, y); vh[4] = (short)x; vl[4] = (short)y;
      split_bf16(f1.y, x, y); vh[5] = (short)x; vl[5] = (short)y;
      split_bf16(f1.z, x, y); vh[6] = (short)x; vl[6] = (short)y;
      split_bf16(f1.w, x, y); vh[7] = (short)x; vl[7] = (short)y;
      const int dst = (((b * 8 + jt) * 8 + ksl) * 64 + lane) * 8;
      *(v8s*)(Sfh + dst) = vh;
      *(v8s*)(Sfl + dst) = vl;
    }
  }
}

__device__ inline void arg_better(float v2, int i2, float& v, int& idx) {
  if (v2 > v || (v2 == v && i2 < idx)) { v = v2; idx = i2; }
}

// LDS A-tile (P part, k<128) fragment-order index: jl (0..63), k (0..127)
__device__ inline int a_idx(int jl, int k) {
  return (((jl >> 5) * 8 + (k >> 4)) * 64 + ((k >> 3) & 1) * 32 + (jl & 31)) * 8
         + (k & 7);
}
// per-i A block: hi at +0, lo at +8192 shorts; i1 block at +16384 shorts.
#define AI 16384
#define ALO 8192

// ---------------------------------------------------------------------------
// score_kernel v13: 2 i per block (i-pair amortization). Same W/B loads feed
// 24 MFMA/ks (vs 12) and B L2 traffic halves — attacks the uncovered-load
// latency that v8-v12 could not pipeline away (compiler re-sinks prefetches;
// VGPR stuck ~90). acc 128 AGPR + ~110 VGPR fits the 2-wave 256-reg budget.
// ---------------------------------------------------------------------------
__global__ __launch_bounds__(256, 2) void score_kernel(
    const float* __restrict__ s,
    const float* __restrict__ Ag, const float* __restrict__ Aa,
    const unsigned short* __restrict__ Sfh, const unsigned short* __restrict__ Sfl,
    const unsigned short* __restrict__ Wghi, const unsigned short* __restrict__ Wglo,
    const unsigned short* __restrict__ Wahi,
    const float* __restrict__ Wg2, const float* __restrict__ bg2p,
    const float* __restrict__ Wa2, const float* __restrict__ ba2p,
    float* __restrict__ out) {
  const int b = blockIdx.x >> 7;
  const int q = blockIdx.x & 127;
  const int i0 = q * 2;
  const int t = threadIdx.x;
  const int wv = t >> 6, lane = t & 63;
  const int m32 = lane & 31, half32 = lane >> 5;

  __shared__ __align__(16) unsigned short a_all[2 * AI + 64]; // i0|i1 P tiles
  __shared__ float si_sh[2 * D_];
  __shared__ float sc_part[1024];      // [ii][ga][wv][jl]
  __shared__ float scg_sh[2 * N_];
  __shared__ float attl_sh[2 * N_];
  __shared__ float red_v[4];
  __shared__ int red_i[4];
  __shared__ int sel_list[2][K_];

  if (t < 2 * D_) si_sh[t] = s[(b * N_ + i0) * D_ + t];  // rows i0,i0+1 contig

  // epilogue tables in VGPRs
  float agv[2][2], aav[2][2], w2g[2], w2a[2];
#pragma unroll
  for (int ht = 0; ht < 2; ht++) {
    const int hg = wv * 64 + ht * 32 + m32;
    w2g[ht] = Wg2[hg];
    w2a[ht] = Wa2[hg];
#pragma unroll
    for (int ii = 0; ii < 2; ii++) {
      agv[ii][ht] = Ag[(b * N_ + i0 + ii) * H_ + hg];
      aav[ii][ht] = Aa[(b * N_ + i0 + ii) * H_ + hg];
    }
  }

  const int boff = ((2 * wv) * 64 + lane) * 8;   // tile pair base; +512 = tile1

#define MF(A_, B_v, C_) C_ = __builtin_amdgcn_mfma_f32_32x32x16_bf16(A_, B_v, C_, 0, 0, 0)

#pragma unroll 1
  for (int ph = 0; ph < 4; ph++) {
    __syncthreads();
    // ---- stage P tiles for both i (frag order, k<128) ----
    {
      const int jl = t >> 2, kq = t & 3;
      const int jg = b * N_ + ph * NJP + jl;
      const float* srow = s + jg * D_ + kq * 32;
#pragma unroll
      for (int ii = 0; ii < 2; ii++) {
        const float* sic = si_sh + ii * D_ + kq * 32;
        unsigned short* base = a_all + ii * AI;
#pragma unroll
        for (int u = 0; u < 4; u++) {
          const float4 sv0 = *(const float4*)(srow + u * 8);
          const float4 sv1 = *(const float4*)(srow + u * 8 + 4);
          v8s vh, vl;
          unsigned short x, y;
          split_bf16(sic[u * 8 + 0] * sv0.x, x, y); vh[0] = (short)x; vl[0] = (short)y;
          split_bf16(sic[u * 8 + 1] * sv0.y, x, y); vh[1] = (short)x; vl[1] = (short)y;
          split_bf16(sic[u * 8 + 2] * sv0.z, x, y); vh[2] = (short)x; vl[2] = (short)y;
          split_bf16(sic[u * 8 + 3] * sv0.w, x, y); vh[3] = (short)x; vl[3] = (short)y;
          split_bf16(sic[u * 8 + 4] * sv1.x, x, y); vh[4] = (short)x; vl[4] = (short)y;
          split_bf16(sic[u * 8 + 5] * sv1.y, x, y); vh[5] = (short)x; vl[5] = (short)y;
          split_bf16(sic[u * 8 + 6] * sv1.z, x, y); vh[6] = (short)x; vl[6] = (short)y;
          split_bf16(sic[u * 8 + 7] * sv1.w, x, y); vh[7] = (short)x; vl[7] = (short)y;
          const int idx = a_idx(jl, kq * 32 + u * 8);
          *(v8s*)(base + idx) = vh;
          *(v8s*)(base + ALO + idx) = vl;
        }
      }
    }
    __syncthreads();

    const unsigned short* sf_base_h = Sfh + ((b * 8 + ph * 2) * 8) * 512 + lane * 8;
    const unsigned short* sf_base_l = Sfl + ((b * 8 + ph * 2) * 8) * 512 + lane * 8;

    // ================= pass G: gate (split-3) ==============================
    {
      v16f acc[2][2][2];   // [ii][jt][ht] — 128 AGPR
#pragma unroll
      for (int ii = 0; ii < 2; ii++)
#pragma unroll
        for (int jt = 0; jt < 2; jt++)
#pragma unroll
          for (int ht = 0; ht < 2; ht++) acc[ii][jt][ht] = (v16f)(0.f);

      const unsigned short* pgh = Wghi + boff;
      const unsigned short* pgl = Wglo + boff;
      v8s bh[2][2], bl[2][2];
      bh[0][0] = *(const v8s*)pgh;  bh[0][1] = *(const v8s*)(pgh + 512);
      bl[0][0] = *(const v8s*)pgl;  bl[0][1] = *(const v8s*)(pgl + 512);
      pgh += 4096;  pgl += 4096;

      const unsigned short* ahp = a_all + lane * 8;
      // ---- loop1: ks 0..7, A from LDS (P, both i) ----
#pragma unroll 2
      for (int ks = 0; ks < 8; ks++) {
        const int cur = ks & 1, nxt = cur ^ 1;
        bh[nxt][0] = *(const v8s*)pgh;  bh[nxt][1] = *(const v8s*)(pgh + 512);
        bl[nxt][0] = *(const v8s*)pgl;  bl[nxt][1] = *(const v8s*)(pgl + 512);
        pgh += 4096;  pgl += 4096;
        v8s a0h0 = *(const v8s*)(ahp);
        v8s a0h1 = *(const v8s*)(ahp + 4096);
        v8s a0l0 = *(const v8s*)(ahp + ALO);
        v8s a0l1 = *(const v8s*)(ahp + ALO + 4096);
        v8s a1h0 = *(const v8s*)(ahp + AI);
        v8s a1h1 = *(const v8s*)(ahp + AI + 4096);
        v8s a1l0 = *(const v8s*)(ahp + AI + ALO);
        v8s a1l1 = *(const v8s*)(ahp + AI + ALO + 4096);
        ahp += 512;
        MF(a0h0, bh[cur][0], acc[0][0][0]); MF(a0h0, bh[cur][1], acc[0][0][1]);
        MF(a0h0, bl[cur][0], acc[0][0][0]); MF(a0h0, bl[cur][1], acc[0][0][1]);
        MF(a0l0, bh[cur][0], acc[0][0][0]); MF(a0l0, bh[cur][1], acc[0][0][1]);
        MF(a0h1, bh[cur][0], acc[0][1][0]); MF(a0h1, bh[cur][1], acc[0][1][1]);
        MF(a0h1, bl[cur][0], acc[0][1][0]); MF(a0h1, bl[cur][1], acc[0][1][1]);
        MF(a0l1, bh[cur][0], acc[0][1][0]); MF(a0l1, bh[cur][1], acc[0][1][1]);
        MF(a1h0, bh[cur][0], acc[1][0][0]); MF(a1h0, bh[cur][1], acc[1][0][1]);
        MF(a1h0, bl[cur][0], acc[1][0][0]); MF(a1h0, bl[cur][1], acc[1][0][1]);
        MF(a1l0, bh[cur][0], acc[1][0][0]); MF(a1l0, bh[cur][1], acc[1][0][1]);
        MF(a1h1, bh[cur][0], acc[1][1][0]); MF(a1h1, bh[cur][1], acc[1][1][1]);
        MF(a1h1, bl[cur][0], acc[1][1][0]); MF(a1h1, bl[cur][1], acc[1][1][1]);
        MF(a1l1, bh[cur][0], acc[1][1][0]); MF(a1l1, bh[cur][1], acc[1][1][1]);
      }
      // ---- loop2: ks 8..15, A from global sj streams (i-independent!) ----
      const unsigned short* sfh = sf_base_h;
      const unsigned short* sfl = sf_base_l;
#pragma unroll 2
      for (int ks = 8; ks < 16; ks++) {
        const int cur = ks & 1, nxt = cur ^ 1;
        bh[nxt][0] = *(const v8s*)pgh;  bh[nxt][1] = *(const v8s*)(pgh + 512);
        bl[nxt][0] = *(const v8s*)pgl;  bl[nxt][1] = *(const v8s*)(pgl + 512);
        pgh += 4096;  pgl += 4096;   // last iter reads pad - harmless
        v8s ah0 = *(const v8s*)(sfh);
        v8s ah1 = *(const v8s*)(sfh + 4096);
        v8s al0 = *(const v8s*)(sfl);
        v8s al1 = *(const v8s*)(sfl + 4096);
        sfh += 512;  sfl += 512;
#pragma unroll
        for (int ii = 0; ii < 2; ii++) {
          MF(ah0, bh[cur][0], acc[ii][0][0]); MF(ah0, bh[cur][1], acc[ii][0][1]);
          MF(ah0, bl[cur][0], acc[ii][0][0]); MF(ah0, bl[cur][1], acc[ii][0][1]);
          MF(al0, bh[cur][0], acc[ii][0][0]); MF(al0, bh[cur][1], acc[ii][0][1]);
          MF(ah1, bh[cur][0], acc[ii][1][0]); MF(ah1, bh[cur][1], acc[ii][1][1]);
          MF(ah1, bl[cur][0], acc[ii][1][0]); MF(ah1, bl[cur][1], acc[ii][1][1]);
          MF(al1, bh[cur][0], acc[ii][1][0]); MF(al1, bh[cur][1], acc[ii][1][1]);
        }
      }
      // wait — loop2's sj A-part differs per i only through P; sj is truly
      // i-independent, but the accumulators already hold the i-specific P
      // contribution from loop1, so sharing A here is correct.
      // epilogue G (per i)
#pragma unroll
      for (int ii = 0; ii < 2; ii++) {
        float sg[32];
#pragma unroll
        for (int m = 0; m < 32; m++) sg[m] = 0.f;
#pragma unroll
        for (int ht = 0; ht < 2; ht++)
#pragma unroll
          for (int jt = 0; jt < 2; jt++)
#pragma unroll
            for (int r = 0; r < 16; r++) {
              const float z = acc[ii][jt][ht][r] + agv[ii][ht];
              sg[jt * 16 + r] = fmaf(fmaxf(z, 0.f), w2g[ht], sg[jt * 16 + r]);
            }
#pragma unroll
        for (int m = 0; m < 32; m++) {
          float v = sg[m];
#pragma unroll
          for (int off = 1; off <= 16; off <<= 1) v += __shfl_xor(v, off, 64);
          sg[m] = v;
        }
        if (m32 == 0) {
#pragma unroll
          for (int jt = 0; jt < 2; jt++)
#pragma unroll
            for (int r = 0; r < 16; r++) {
              const int jl = jt * 32 + (r & 3) + 8 * (r >> 2) + 4 * half32;
              sc_part[(ii * 2 + 0) * 256 + wv * NJP + jl] = sg[jt * 16 + r];
            }
        }
      }
    }

    // ================= pass A: att (hi-only) ===============================
    {
      v16f acc[2][2][2];
#pragma unroll
      for (int ii = 0; ii < 2; ii++)
#pragma unroll
        for (int jt = 0; jt < 2; jt++)
#pragma unroll
          for (int ht = 0; ht < 2; ht++) acc[ii][jt][ht] = (v16f)(0.f);

      const unsigned short* pah = Wahi + boff;
      v8s bh[2][2];
      bh[0][0] = *(const v8s*)pah;  bh[0][1] = *(const v8s*)(pah + 512);
      pah += 4096;

      const unsigned short* ahp = a_all + lane * 8;
#pragma unroll 2
      for (int ks = 0; ks < 8; ks++) {
        const int cur = ks & 1, nxt = cur ^ 1;
        bh[nxt][0] = *(const v8s*)pah;  bh[nxt][1] = *(const v8s*)(pah + 512);
        pah += 4096;
        v8s a0h0 = *(const v8s*)(ahp);
        v8s a0h1 = *(const v8s*)(ahp + 4096);
        v8s a1h0 = *(const v8s*)(ahp + AI);
        v8s a1h1 = *(const v8s*)(ahp + AI + 4096);
        ahp += 512;
        MF(a0h0, bh[cur][0], acc[0][0][0]); MF(a0h0, bh[cur][1], acc[0][0][1]);
        MF(a0h1, bh[cur][0], acc[0][1][0]); MF(a0h1, bh[cur][1], acc[0][1][1]);
        MF(a1h0, bh[cur][0], acc[1][0][0]); MF(a1h0, bh[cur][1], acc[1][0][1]);
        MF(a1h1, bh[cur][0], acc[1][1][0]); MF(a1h1, bh[cur][1], acc[1][1][1]);
      }
      const unsigned short* sfh = sf_base_h;
#pragma unroll 2
      for (int ks = 8; ks < 16; ks++) {
        const int cur = ks & 1, nxt = cur ^ 1;
        bh[nxt][0] = *(const v8s*)pah;  bh[nxt][1] = *(const v8s*)(pah + 512);
        pah += 4096;   // last iter reads pad
        v8s ah0 = *(const v8s*)(sfh);
        v8s ah1 = *(const v8s*)(sfh + 4096);
        sfh += 512;
#pragma unroll
        for (int ii = 0; ii < 2; ii++) {
          MF(ah0, bh[cur][0], acc[ii][0][0]); MF(ah0, bh[cur][1], acc[ii][0][1]);
          MF(ah1, bh[cur][0], acc[ii][1][0]); MF(ah1, bh[cur][1], acc[ii][1][1]);
        }
      }
      // epilogue A (per i)
#pragma unroll
      for (int ii = 0; ii < 2; ii++) {
        float sa[32];
#pragma unroll
        for (int m = 0; m < 32; m++) sa[m] = 0.f;
#pragma unroll
        for (int ht = 0; ht < 2; ht++)
#pragma unroll
          for (int jt = 0; jt < 2; jt++)
#pragma unroll
            for (int r = 0; r < 16; r++) {
              const float z = acc[ii][jt][ht][r] + aav[ii][ht];
              sa[jt * 16 + r] = fmaf(fmaxf(z, 0.f), w2a[ht], sa[jt * 16 + r]);
            }
#pragma unroll
        for (int m = 0; m < 32; m++) {
          float v = sa[m];
#pragma unroll
          for (int off = 1; off <= 16; off <<= 1) v += __shfl_xor(v, off, 64);
          sa[m] = v;
        }
        if (m32 == 0) {
#pragma unroll
          for (int jt = 0; jt < 2; jt++)
#pragma unroll
            for (int r = 0; r < 16; r++) {
              const int jl = jt * 32 + (r & 3) + 8 * (r >> 2) + 4 * half32;
              sc_part[(ii * 2 + 1) * 256 + wv * NJP + jl] = sa[jt * 16 + r];
            }
        }
      }
    }
    __syncthreads();
    if (t < 2 * NJP) {              // t<128: ii = t>>6, jl = t&63
      const int ii = t >> 6, jl = t & 63;
      float g = bg2p[0], a = ba2p[0];
#pragma unroll
      for (int w = 0; w < 4; w++) {
        g += sc_part[(ii * 2 + 0) * 256 + w * NJP + jl];
        a += sc_part[(ii * 2 + 1) * 256 + w * NJP + jl];
      }
      scg_sh[ii * N_ + ph * NJP + jl] = g;
      attl_sh[ii * N_ + ph * NJP + jl] = a;
    }
  }
  __syncthreads();

  // ---- top-8 per i: value desc, index asc ----
#pragma unroll 1
  for (int ii = 0; ii < 2; ii++) {
    for (int k = 0; k < K_; k++) {
      float v = scg_sh[ii * N_ + t];
      int idx = t;
#pragma unroll
      for (int off = 32; off > 0; off >>= 1) {
        const float vo = __shfl_down(v, off, 64);
        const int io = __shfl_down(idx, off, 64);
        arg_better(vo, io, v, idx);
      }
      if (lane == 0) { red_v[wv] = v; red_i[wv] = idx; }
      __syncthreads();
      if (t == 0) {
        float bv = red_v[0];
        int bi = red_i[0];
        for (int w = 1; w < 4; w++) arg_better(red_v[w], red_i[w], bv, bi);
        sel_list[ii][k] = bi;
        scg_sh[ii * N_ + bi] = -INFINITY;
      }
      __syncthreads();
    }
  }

  float* __restrict__ ctx_out = out;
  float* __restrict__ gate_out = out + B_ * N_ * D_;
  float* __restrict__ att_out = out + B_ * N_ * D_ + B_ * N_ * N_;

#pragma unroll 1
  for (int ii = 0; ii < 2; ii++) {
    bool selj = false;
#pragma unroll
    for (int k = 0; k < K_; k++) selj = selj || (sel_list[ii][k] == t);

    if (t == 0) {
      float m = -INFINITY;
      for (int k = 0; k < K_; k++) m = fmaxf(m, attl_sh[ii * N_ + sel_list[ii][k]]);
      float ssum = 0.f;
      for (int k = 0; k < K_; k++) ssum += expf(attl_sh[ii * N_ + sel_list[ii][k]] - m);
      red_v[0] = m;
      red_v[1] = ssum;
    }
    __syncthreads();
    const float att = selj ? expf(attl_sh[ii * N_ + t] - red_v[0]) / red_v[1] : 0.f;

    const int row = (b * N_ + i0 + ii) * N_;
    gate_out[row + t] = selj ? 1.f : 0.f;
    att_out[row + t] = att;

    __syncthreads();
    attl_sh[ii * N_ + t] = att;
    __syncthreads();
  }

  if (t < D_) {
#pragma unroll 1
    for (int ii = 0; ii < 2; ii++) {
      float acc2 = 0.f;
#pragma unroll
      for (int k = 0; k < K_; k++) {
        const int jj = sel_list[ii][k];
        acc2 = fmaf(attl_sh[ii * N_ + jj], s[(b * N_ + jj) * D_ + t], acc2);
      }
      ctx_out[(b * N_ + i0 + ii) * D_ + t] = acc2;
    }
  }
#undef MF
}

extern "C" void kernel_launch(void* const* d_in, const int* in_sizes, int n_in,
                              void* d_out, int out_size, void* d_ws, size_t ws_size,
                              hipStream_t stream) {
  const float* s   = (const float*)d_in[0];
  const float* Wg1 = (const float*)d_in[1];
  const float* bg1 = (const float*)d_in[2];
  const float* Wg2 = (const float*)d_in[3];
  const float* bg2 = (const float*)d_in[4];
  const float* Wa1 = (const float*)d_in[5];
  const float* ba1 = (const float*)d_in[6];
  const float* Wa2 = (const float*)d_in[7];
  const float* ba2 = (const float*)d_in[8];
  float* out = (float*)d_out;

  float* ws = (float*)d_ws;
  float* Ag = ws;                                        // B*N*H floats
  float* Aa = Ag + B_ * N_ * H_;                         // B*N*H floats
  // W arrays padded by 4096 shorts: 1-deep ks-prefetch reads past the end.
  unsigned short* Wghi = (unsigned short*)(Aa + B_ * N_ * H_);  // 65536+4096
  unsigned short* Wglo = Wghi + 65536 + 4096;
  unsigned short* Wahi = Wglo + 65536 + 4096;
  unsigned short* Sfh  = Wahi + 65536 + 4096;            // B*32768
  unsigned short* Sfl  = Sfh + B_ * 32768;

  prep_all<<<dim3(1184), dim3(256), 0, stream>>>(
      s, Wg1, bg1, Wa1, ba1, Ag, Aa, Wghi, Wglo, Wahi, Sfh, Sfl);
  score_kernel<<<dim3(B_ * 128), dim3(256), 0, stream>>>(
      s, Ag, Aa, Sfh, Sfl, Wghi, Wglo, Wahi, Wg2, bg2, Wa2, ba2, out);
}

// Round 14
// 241.417 us; speedup vs baseline: 1.4403x; 1.0288x over previous
//
#include <hip/hip_runtime.h>
#include <math.h>

#define B_ 4
#define N_ 256
#define D_ 128
#define H_ 256
#define K_ 8
#define NJP 64    // j per phase (4 phases)

typedef short v8s __attribute__((ext_vector_type(8)));    // 8 bf16 = 4 VGPRs
typedef float v16f __attribute__((ext_vector_type(16)));  // 32x32 MFMA acc

// hi = top-16-bit truncation (x - hi is EXACT); lo = RNE bf16 of remainder.
__device__ inline void split_bf16(float x, unsigned short& hi, unsigned short& lo) {
  unsigned u = __float_as_uint(x);
  unsigned uh = u & 0xFFFF0000u;
  hi = (unsigned short)(uh >> 16);
  float r = x - __uint_as_float(uh);
  unsigned ur = __float_as_uint(r);
  ur += 0x7FFFu + ((ur >> 16) & 1u);
  lo = (unsigned short)(ur >> 16);
}

// ---------------------------------------------------------------------------
// prep_all: ONE launch for all preprocessing.
//  blocks 0..1023   : Ag/Aa (i-side first-layer terms, bias folded)
//  blocks 1024..1151: W -> MFMA-B fragment order [ks(16)][tile(8)][lane][8]
//  blocks 1152..1183: sj half of A (i-independent) -> MFMA-A fragment order
// ---------------------------------------------------------------------------
__global__ __launch_bounds__(256) void prep_all(
    const float* __restrict__ s,
    const float* __restrict__ Wg1, const float* __restrict__ bg1,
    const float* __restrict__ Wa1, const float* __restrict__ ba1,
    float* __restrict__ Ag, float* __restrict__ Aa,
    unsigned short* __restrict__ Wghi, unsigned short* __restrict__ Wglo,
    unsigned short* __restrict__ Wahi,
    unsigned short* __restrict__ Sfh, unsigned short* __restrict__ Sfl) {
  __shared__ float sh[D_];
  const int blk = blockIdx.x;
  if (blk < 1024) {
    const int b = blk >> 8, n = blk & 255, h = threadIdx.x;
    if (h < D_) sh[h] = s[(b * N_ + n) * D_ + h];
    __syncthreads();
    float ag = bg1[h], aa = ba1[h];
#pragma unroll 8
    for (int d = 0; d < D_; d++) {
      ag = fmaf(sh[d], Wg1[d * H_ + h], ag);
      aa = fmaf(sh[d], Wa1[d * H_ + h], aa);
    }
    Ag[(b * N_ + n) * H_ + h] = ag;
    Aa[(b * N_ + n) * H_ + h] = aa;
  } else if (blk < 1152) {
    const int id = blk - 1024;          // 0..127
    if (threadIdx.x < 64) {
      const int ks = id >> 3, tile = id & 7, lane = threadIdx.x;
      const int h = tile * 32 + (lane & 31);
      const int kbase = ks * 16 + (lane >> 5) * 8;
      const int idx0 = (id * 64 + lane) * 8;
#pragma unroll
      for (int e = 0; e < 8; e++) {
        const int k = kbase + e;
        const int f = (k < D_) ? (2 * D_ + k) : k;
        unsigned short x, y;
        split_bf16(Wg1[f * H_ + h], x, y);
        Wghi[idx0 + e] = x;
        Wglo[idx0 + e] = y;
        unsigned short xa, ya;
        split_bf16(Wa1[f * H_ + h], xa, ya);
        Wahi[idx0 + e] = xa;
      }
    }
  } else {
    const int id = blk - 1152;          // 0..31
    const int b = id >> 3, jt = id & 7;
    const int lane = threadIdx.x & 63, k0 = threadIdx.x >> 6;
    const int j = jt * 32 + (lane & 31);
#pragma unroll
    for (int ksl = k0; ksl < 8; ksl += 4) {
      const int d = ksl * 16 + (lane >> 5) * 8;
      const float* sp = s + (b * N_ + j) * D_ + d;
      const float4 f0 = *(const float4*)(sp);
      const float4 f1 = *(const float4*)(sp + 4);
      v8s vh, vl;
      unsigned short x, y;
      split_bf16(f0.x, x, y); vh[0] = (short)x; vl[0] = (short)y;
      split_bf16(f0.y, x, y); vh[1] = (short)x; vl[1] = (short)y;
      split_bf16(f0.z, x, y); vh[2] = (short)x; vl[2] = (short)y;
      split_bf16(f0.w, x, y); vh[3] = (short)x; vl[3] = (short)y;
      split_bf16(f1.x, x, y); vh[4] = (short)x; vl[4] = (short)y;
      split_bf16(f1.y, x, y); vh[5] = (short)x; vl[5] = (short)y;
      split_bf16(f1.z, x, y); vh[6] = (short)x; vl[6] = (short)y;
      split_bf16(f1.w, x, y); vh[7] = (short)x; vl[7] = (short)y;
      const int dst = (((b * 8 + jt) * 8 + ksl) * 64 + lane) * 8;
      *(v8s*)(Sfh + dst) = vh;
      *(v8s*)(Sfl + dst) = vl;
    }
  }
}

__device__ inline void arg_better(float v2, int i2, float& v, int& idx) {
  if (v2 > v || (v2 == v && i2 < idx)) { v = v2; idx = i2; }
}

// LDS A-tile (P part, k<128) fragment-order index: jl (0..63), k (0..127)
__device__ inline int a_idx(int jl, int k) {
  return (((jl >> 5) * 8 + (k >> 4)) * 64 + ((k >> 3) & 1) * 32 + (jl & 31)) * 8
         + (k & 7);
}
#define ALO 8192   // shorts offset of lo half

// ---------------------------------------------------------------------------
// score_kernel v14: single i per block, gate+att MERGED into one k-loop.
// Each A-fragment read feeds 16 MFMAs (12 gate split-3 + 4 att hi-only)
// instead of two separate passes (12 then 8) — halves A LDS traffic and
// barrier count per phase, overlaps B streams of both nets. acc = 128 AGPR
// (64 g + 64 a) + ~120 VGPR fits the 2-wave 256-reg budget.
// ---------------------------------------------------------------------------
__global__ __launch_bounds__(256, 2) void score_kernel(
    const float* __restrict__ s,
    const float* __restrict__ Ag, const float* __restrict__ Aa,
    const unsigned short* __restrict__ Sfh, const unsigned short* __restrict__ Sfl,
    const unsigned short* __restrict__ Wghi, const unsigned short* __restrict__ Wglo,
    const unsigned short* __restrict__ Wahi,
    const float* __restrict__ Wg2, const float* __restrict__ bg2p,
    const float* __restrict__ Wa2, const float* __restrict__ ba2p,
    float* __restrict__ out) {
  const int b = blockIdx.x >> 8;
  const int i = blockIdx.x & 255;
  const int t = threadIdx.x;
  const int wv = t >> 6, lane = t & 63;
  const int m32 = lane & 31, half32 = lane >> 5;

  __shared__ __align__(16) unsigned short a_all[2 * ALO + 64]; // P hi|lo 32KB
  __shared__ float si_sh[D_];
  __shared__ float sc_part[8 * NJP];   // [0..3]=gate per wave, [4..7]=att
  __shared__ float scg_sh[N_];
  __shared__ float attl_sh[N_];
  __shared__ float red_v[4];
  __shared__ int red_i[4];
  __shared__ int sel_list[K_];

  if (t < D_) si_sh[t] = s[(b * N_ + i) * D_ + t];

  // epilogue tables in VGPRs (phase-independent h index)
  float agv[2], w2g[2], aav[2], w2a[2];
#pragma unroll
  for (int ht = 0; ht < 2; ht++) {
    const int hg = wv * 64 + ht * 32 + m32;
    agv[ht] = Ag[(b * N_ + i) * H_ + hg];
    w2g[ht] = Wg2[hg];
    aav[ht] = Aa[(b * N_ + i) * H_ + hg];
    w2a[ht] = Wa2[hg];
  }

  const int boff = ((2 * wv) * 64 + lane) * 8;   // tile pair base; +512 = tile1

#define MF(A_, B_v, C_) C_ = __builtin_amdgcn_mfma_f32_32x32x16_bf16(A_, B_v, C_, 0, 0, 0)

#pragma unroll 1
  for (int ph = 0; ph < 4; ph++) {
    __syncthreads();
    // ---- stage P tile (frag order, k<128 only) ----
    {
      const int jl = t >> 2, kq = t & 3;
      const int jg = b * N_ + ph * NJP + jl;
      const float* srow = s + jg * D_ + kq * 32;
      const float* sic = si_sh + kq * 32;
#pragma unroll
      for (int u = 0; u < 4; u++) {   // 8 k per u
        const float4 sv0 = *(const float4*)(srow + u * 8);
        const float4 sv1 = *(const float4*)(srow + u * 8 + 4);
        v8s vh, vl;
        unsigned short x, y;
        split_bf16(sic[u * 8 + 0] * sv0.x, x, y); vh[0] = (short)x; vl[0] = (short)y;
        split_bf16(sic[u * 8 + 1] * sv0.y, x, y); vh[1] = (short)x; vl[1] = (short)y;
        split_bf16(sic[u * 8 + 2] * sv0.z, x, y); vh[2] = (short)x; vl[2] = (short)y;
        split_bf16(sic[u * 8 + 3] * sv0.w, x, y); vh[3] = (short)x; vl[3] = (short)y;
        split_bf16(sic[u * 8 + 4] * sv1.x, x, y); vh[4] = (short)x; vl[4] = (short)y;
        split_bf16(sic[u * 8 + 5] * sv1.y, x, y); vh[5] = (short)x; vl[5] = (short)y;
        split_bf16(sic[u * 8 + 6] * sv1.z, x, y); vh[6] = (short)x; vl[6] = (short)y;
        split_bf16(sic[u * 8 + 7] * sv1.w, x, y); vh[7] = (short)x; vl[7] = (short)y;
        const int idx = a_idx(jl, kq * 32 + u * 8);
        *(v8s*)(a_all + idx) = vh;
        *(v8s*)(a_all + ALO + idx) = vl;
      }
    }
    __syncthreads();

    const unsigned short* sf_base_h = Sfh + ((b * 8 + ph * 2) * 8) * 512 + lane * 8;
    const unsigned short* sf_base_l = Sfl + ((b * 8 + ph * 2) * 8) * 512 + lane * 8;

    // ========== merged k-loop: gate (split-3) + att (hi) together ==========
    v16f g00, g01, g10, g11, a00, a01, a10, a11;   // [jt][ht] — 128 AGPR
    g00 = g01 = g10 = g11 = (v16f)(0.f);
    a00 = a01 = a10 = a11 = (v16f)(0.f);

    {
      const unsigned short* pgh = Wghi + boff;
      const unsigned short* pgl = Wglo + boff;
      const unsigned short* pah = Wahi + boff;
      v8s bh[2][2], bl[2][2], ba[2][2];
      bh[0][0] = *(const v8s*)pgh;  bh[0][1] = *(const v8s*)(pgh + 512);
      bl[0][0] = *(const v8s*)pgl;  bl[0][1] = *(const v8s*)(pgl + 512);
      ba[0][0] = *(const v8s*)pah;  ba[0][1] = *(const v8s*)(pah + 512);
      pgh += 4096;  pgl += 4096;  pah += 4096;

      const unsigned short* ahp = a_all + lane * 8;
      // ---- loop1: ks 0..7, A from LDS (P part) ----
#pragma unroll 2
      for (int ks = 0; ks < 8; ks++) {
        const int cur = ks & 1, nxt = cur ^ 1;
        bh[nxt][0] = *(const v8s*)pgh;  bh[nxt][1] = *(const v8s*)(pgh + 512);
        bl[nxt][0] = *(const v8s*)pgl;  bl[nxt][1] = *(const v8s*)(pgl + 512);
        ba[nxt][0] = *(const v8s*)pah;  ba[nxt][1] = *(const v8s*)(pah + 512);
        pgh += 4096;  pgl += 4096;  pah += 4096;
        v8s ah0 = *(const v8s*)(ahp);
        v8s ah1 = *(const v8s*)(ahp + 4096);
        v8s al0 = *(const v8s*)(ahp + ALO);
        v8s al1 = *(const v8s*)(ahp + ALO + 4096);
        ahp += 512;
        MF(ah0, bh[cur][0], g00); MF(ah0, bh[cur][1], g01);
        MF(ah0, ba[cur][0], a00); MF(ah0, ba[cur][1], a01);
        MF(ah0, bl[cur][0], g00); MF(ah0, bl[cur][1], g01);
        MF(al0, bh[cur][0], g00); MF(al0, bh[cur][1], g01);
        MF(ah1, bh[cur][0], g10); MF(ah1, bh[cur][1], g11);
        MF(ah1, ba[cur][0], a10); MF(ah1, ba[cur][1], a11);
        MF(ah1, bl[cur][0], g10); MF(ah1, bl[cur][1], g11);
        MF(al1, bh[cur][0], g10); MF(al1, bh[cur][1], g11);
      }
      // ---- loop2: ks 8..15, A from global sj frag streams ----
      const unsigned short* sfh = sf_base_h;
      const unsigned short* sfl = sf_base_l;
#pragma unroll 2
      for (int ks = 8; ks < 16; ks++) {
        const int cur = ks & 1, nxt = cur ^ 1;
        bh[nxt][0] = *(const v8s*)pgh;  bh[nxt][1] = *(const v8s*)(pgh + 512);
        bl[nxt][0] = *(const v8s*)pgl;  bl[nxt][1] = *(const v8s*)(pgl + 512);
        ba[nxt][0] = *(const v8s*)pah;  ba[nxt][1] = *(const v8s*)(pah + 512);
        pgh += 4096;  pgl += 4096;  pah += 4096;   // last iter reads pad
        v8s ah0 = *(const v8s*)(sfh);
        v8s ah1 = *(const v8s*)(sfh + 4096);
        v8s al0 = *(const v8s*)(sfl);
        v8s al1 = *(const v8s*)(sfl + 4096);
        sfh += 512;  sfl += 512;
        MF(ah0, bh[cur][0], g00); MF(ah0, bh[cur][1], g01);
        MF(ah0, ba[cur][0], a00); MF(ah0, ba[cur][1], a01);
        MF(ah0, bl[cur][0], g00); MF(ah0, bl[cur][1], g01);
        MF(al0, bh[cur][0], g00); MF(al0, bh[cur][1], g01);
        MF(ah1, bh[cur][0], g10); MF(ah1, bh[cur][1], g11);
        MF(ah1, ba[cur][0], a10); MF(ah1, ba[cur][1], a11);
        MF(ah1, bl[cur][0], g10); MF(ah1, bl[cur][1], g11);
        MF(al1, bh[cur][0], g10); MF(al1, bh[cur][1], g11);
      }
    }

    // ---- merged epilogue: relu + W2 dot, 16-lane butterfly, both nets ----
    {
      float sg[32];
#pragma unroll
      for (int m = 0; m < 32; m++) sg[m] = 0.f;
#pragma unroll
      for (int r = 0; r < 16; r++) {
        sg[r]      = fmaf(fmaxf(g00[r] + agv[0], 0.f), w2g[0], sg[r]);
        sg[r]      = fmaf(fmaxf(g01[r] + agv[1], 0.f), w2g[1], sg[r]);
        sg[16 + r] = fmaf(fmaxf(g10[r] + agv[0], 0.f), w2g[0], sg[16 + r]);
        sg[16 + r] = fmaf(fmaxf(g11[r] + agv[1], 0.f), w2g[1], sg[16 + r]);
      }
#pragma unroll
      for (int m = 0; m < 32; m++) {
        float v = sg[m];
#pragma unroll
        for (int off = 1; off <= 16; off <<= 1) v += __shfl_xor(v, off, 64);
        sg[m] = v;
      }
      if (m32 == 0) {
#pragma unroll
        for (int jt = 0; jt < 2; jt++)
#pragma unroll
          for (int r = 0; r < 16; r++) {
            const int jl = jt * 32 + (r & 3) + 8 * (r >> 2) + 4 * half32;
            sc_part[wv * NJP + jl] = sg[jt * 16 + r];
          }
      }
      float sa[32];
#pragma unroll
      for (int m = 0; m < 32; m++) sa[m] = 0.f;
#pragma unroll
      for (int r = 0; r < 16; r++) {
        sa[r]      = fmaf(fmaxf(a00[r] + aav[0], 0.f), w2a[0], sa[r]);
        sa[r]      = fmaf(fmaxf(a01[r] + aav[1], 0.f), w2a[1], sa[r]);
        sa[16 + r] = fmaf(fmaxf(a10[r] + aav[0], 0.f), w2a[0], sa[16 + r]);
        sa[16 + r] = fmaf(fmaxf(a11[r] + aav[1], 0.f), w2a[1], sa[16 + r]);
      }
#pragma unroll
      for (int m = 0; m < 32; m++) {
        float v = sa[m];
#pragma unroll
        for (int off = 1; off <= 16; off <<= 1) v += __shfl_xor(v, off, 64);
        sa[m] = v;
      }
      if (m32 == 0) {
#pragma unroll
        for (int jt = 0; jt < 2; jt++)
#pragma unroll
          for (int r = 0; r < 16; r++) {
            const int jl = jt * 32 + (r & 3) + 8 * (r >> 2) + 4 * half32;
            sc_part[4 * NJP + wv * NJP + jl] = sa[jt * 16 + r];
          }
      }
    }
    __syncthreads();
    if (t < NJP) {
      scg_sh[ph * NJP + t] = sc_part[t] + sc_part[NJP + t] + sc_part[2 * NJP + t]
                           + sc_part[3 * NJP + t] + bg2p[0];
      attl_sh[ph * NJP + t] = sc_part[4 * NJP + t] + sc_part[5 * NJP + t]
                            + sc_part[6 * NJP + t] + sc_part[7 * NJP + t] + ba2p[0];
    }
  }
  __syncthreads();

  // ---- top-8 over j: value desc, index asc ----
  for (int k = 0; k < K_; k++) {
    float v = scg_sh[t];
    int idx = t;
#pragma unroll
    for (int off = 32; off > 0; off >>= 1) {
      const float vo = __shfl_down(v, off, 64);
      const int io = __shfl_down(idx, off, 64);
      arg_better(vo, io, v, idx);
    }
    if ((t & 63) == 0) { red_v[t >> 6] = v; red_i[t >> 6] = idx; }
    __syncthreads();
    if (t == 0) {
      float bv = red_v[0];
      int bi = red_i[0];
      for (int w = 1; w < 4; w++) arg_better(red_v[w], red_i[w], bv, bi);
      sel_list[k] = bi;
      scg_sh[bi] = -INFINITY;
    }
    __syncthreads();
  }

  bool selj = false;
#pragma unroll
  for (int k = 0; k < K_; k++) selj = selj || (sel_list[k] == t);

  if (t == 0) {
    float m = -INFINITY;
    for (int k = 0; k < K_; k++) m = fmaxf(m, attl_sh[sel_list[k]]);
    float ssum = 0.f;
    for (int k = 0; k < K_; k++) ssum += expf(attl_sh[sel_list[k]] - m);
    red_v[0] = m;
    red_v[1] = ssum;
  }
  __syncthreads();
  const float att = selj ? expf(attl_sh[t] - red_v[0]) / red_v[1] : 0.f;

  float* __restrict__ ctx_out = out;
  float* __restrict__ gate_out = out + B_ * N_ * D_;
  float* __restrict__ att_out = out + B_ * N_ * D_ + B_ * N_ * N_;

  const int row = (b * N_ + i) * N_;
  gate_out[row + t] = selj ? 1.f : 0.f;
  att_out[row + t] = att;

  __syncthreads();
  attl_sh[t] = att;
  __syncthreads();

  if (t < D_) {
    float acc2 = 0.f;
#pragma unroll
    for (int k = 0; k < K_; k++) {
      const int jj = sel_list[k];
      acc2 = fmaf(attl_sh[jj], s[(b * N_ + jj) * D_ + t], acc2);
    }
    ctx_out[(b * N_ + i) * D_ + t] = acc2;
  }
#undef MF
}

extern "C" void kernel_launch(void* const* d_in, const int* in_sizes, int n_in,
                              void* d_out, int out_size, void* d_ws, size_t ws_size,
                              hipStream_t stream) {
  const float* s   = (const float*)d_in[0];
  const float* Wg1 = (const float*)d_in[1];
  const float* bg1 = (const float*)d_in[2];
  const float* Wg2 = (const float*)d_in[3];
  const float* bg2 = (const float*)d_in[4];
  const float* Wa1 = (const float*)d_in[5];
  const float* ba1 = (const float*)d_in[6];
  const float* Wa2 = (const float*)d_in[7];
  const float* ba2 = (const float*)d_in[8];
  float* out = (float*)d_out;

  float* ws = (float*)d_ws;
  float* Ag = ws;                                        // B*N*H floats
  float* Aa = Ag + B_ * N_ * H_;                         // B*N*H floats
  // W arrays padded by 4096 shorts: 1-deep ks-prefetch reads past the end.
  unsigned short* Wghi = (unsigned short*)(Aa + B_ * N_ * H_);  // 65536+4096
  unsigned short* Wglo = Wghi + 65536 + 4096;
  unsigned short* Wahi = Wglo + 65536 + 4096;
  unsigned short* Sfh  = Wahi + 65536 + 4096;            // B*32768
  unsigned short* Sfl  = Sfh + B_ * 32768;

  prep_all<<<dim3(1184), dim3(256), 0, stream>>>(
      s, Wg1, bg1, Wa1, ba1, Ag, Aa, Wghi, Wglo, Wahi, Sfh, Sfl);
  score_kernel<<<dim3(B_ * N_), dim3(256), 0, stream>>>(
      s, Ag, Aa, Sfh, Sfl, Wghi, Wglo, Wahi, Wg2, bg2, Wa2, ba2, out);
}